// Round 5
// baseline (1003.412 us; speedup 1.0000x reference)
//
#include <hip/hip_runtime.h>
#include <stdint.h>
#include <math.h>

#define NTOK 4096
#define DIM  1024
#define NEXP 64
#define KSEL 6
#define FF   1408
#define FF2  2816
#define DFFC 4096
#define CAPE 768

typedef __bf16 bf16x8 __attribute__((ext_vector_type(8)));
typedef float  f32x4  __attribute__((ext_vector_type(4)));

__device__ __forceinline__ float bf2f(uint32_t h) {
  union { uint32_t u; float f; } v; v.u = h << 16; return v.f;
}
__device__ __forceinline__ uint16_t f2bf(float f) {
  union { float f; uint32_t u; } v; v.f = f;
  return (uint16_t)((v.u + 0x7fffu + ((v.u >> 16) & 1u)) >> 16);
}
// packed RNE f32->bf16 pair (low = a, high = b)
__device__ __forceinline__ uint32_t pk_bf16(float a, float b) {
  uint32_t r;
  asm("v_cvt_pk_bf16_f32 %0, %1, %2" : "=v"(r) : "v"(a), "v"(b));
  return r;
}
// LDS XOR swizzle in halves (bits 3-5), proven conflict-free in r3
__device__ __forceinline__ int swzh(int r) { return ((r ^ (r >> 2)) & 7) << 3; }

__device__ __forceinline__ void load_lds16(const void* g, void* l) {
  __builtin_amdgcn_global_load_lds((const __attribute__((address_space(1))) void*)g,
                                   (__attribute__((address_space(3))) void*)l, 16, 0, 0);
}

// ---------------- router: logits, top-6, gating, z partial, bf16 x ----------------
__global__ __launch_bounds__(256) void router_kernel(const float* __restrict__ x,
                                                     const float* __restrict__ rw,
                                                     int* __restrict__ topk,
                                                     uint16_t* __restrict__ gating,
                                                     float* __restrict__ tokz,
                                                     uint16_t* __restrict__ hb) {
  __shared__ float hs[16 * DIM];
  __shared__ float lg[16][NEXP];
  const int tid = threadIdx.x;
  const int t0 = blockIdx.x * 16;
  const float4* xin = (const float4*)(x + (size_t)t0 * DIM);
  float4* hs4 = (float4*)hs;
  for (int i = tid; i < 16 * DIM / 4; i += 256) hs4[i] = xin[i];
  __syncthreads();
  {
    ushort4* hbo = (ushort4*)(hb + (size_t)t0 * DIM);
    for (int i = tid; i < 16 * DIM / 4; i += 256) {
      float4 v = hs4[i];
      ushort4 o;
      o.x = f2bf(v.x); o.y = f2bf(v.y); o.z = f2bf(v.z); o.w = f2bf(v.w);
      hbo[i] = o;
    }
  }
  const int e = tid >> 2, q = tid & 3;
  float part[16];
#pragma unroll
  for (int tt = 0; tt < 16; tt++) part[tt] = 0.f;
  const float4* rw4 = (const float4*)(rw + (size_t)e * DIM + q * 256);
  for (int i = 0; i < 64; i++) {
    float4 w = rw4[i];
#pragma unroll
    for (int tt = 0; tt < 16; tt++) {
      float4 h = *(const float4*)(hs + tt * DIM + q * 256 + i * 4);
      part[tt] += h.x * w.x + h.y * w.y + h.z * w.z + h.w * w.w;
    }
  }
#pragma unroll
  for (int tt = 0; tt < 16; tt++) {
    float v = part[tt];
    v += __shfl_xor(v, 1);
    v += __shfl_xor(v, 2);
    if (q == 0) lg[tt][e] = v;
  }
  __syncthreads();
  const int wid = tid >> 6, lane = tid & 63;
  for (int ti = 0; ti < 4; ti++) {
    int tt = wid * 4 + ti;
    float v = lg[tt][lane];
    float z = v * v;
#pragma unroll
    for (int off = 32; off; off >>= 1) z += __shfl_xor(z, off);
    float bv[KSEL]; int bi[KSEL];
#pragma unroll
    for (int s = 0; s < KSEL; s++) {
      float m = v; int mi = lane;
#pragma unroll
      for (int off = 32; off; off >>= 1) {
        float om = __shfl_xor(m, off); int oi = __shfl_xor(mi, off);
        if (om > m || (om == m && oi < mi)) { m = om; mi = oi; }
      }
      bv[s] = m; bi[s] = mi;
      if (lane == mi) v = -3.0e38f;
    }
    if (lane == 0) {
      int t = t0 + tt;
      tokz[t] = z;
      float mx = bv[0];
      float ex[KSEL], sum = 0.f;
#pragma unroll
      for (int s = 0; s < KSEL; s++) { ex[s] = expf(bv[s] - mx); sum += ex[s]; }
      float inv = 1.f / sum;
#pragma unroll
      for (int s = 0; s < KSEL; s++) {
        topk[t * KSEL + s] = bi[s];
        gating[t * KSEL + s] = f2bf(ex[s] * inv);
      }
    }
  }
}

// ---------------- z_loss reduce ----------------
__global__ __launch_bounds__(256) void zred_kernel(const float* __restrict__ tz,
                                                   float* __restrict__ out) {
  __shared__ float s[256];
  float a = 0.f;
  for (int i = threadIdx.x; i < NTOK; i += 256) a += tz[i];
  s[threadIdx.x] = a; __syncthreads();
  for (int st = 128; st; st >>= 1) {
    if (threadIdx.x < (unsigned)st) s[threadIdx.x] += s[threadIdx.x + st];
    __syncthreads();
  }
  if (threadIdx.x == 0) out[0] = s[0] * (1e-6f / ((float)NTOK * (float)NEXP));
}

// ---------------- dispatch: stable rank within expert ----------------
__global__ __launch_bounds__(64) void dispatch_kernel(const int* __restrict__ topk,
                                                      int* __restrict__ dest,
                                                      int* __restrict__ invmap,
                                                      int* __restrict__ counts) {
  const int e = blockIdx.x;
  const int lane = threadIdx.x;
  int base = 0;
  for (int it = 0; it < (NTOK * KSEL) / 64; it++) {
    int p = it * 64 + lane;
    int ex = topk[p];
    bool m = (ex == e);
    unsigned long long mask = __ballot(m);
    if (m) {
      int intra = base + __popcll(mask & ((1ull << lane) - 1ull));
      if (intra < CAPE) {
        dest[p] = e * CAPE + intra;
        invmap[e * CAPE + intra] = p / KSEL;
      } else {
        dest[p] = -1;
      }
    }
    base += __popcll(mask);
  }
  if (lane == 0) counts[e] = base < CAPE ? base : CAPE;
}

// ---------------- 8-phase 256x256x64 GEMM, 512 thr (2x4 waves), LDS 128 KiB ----------
// C[M,N] = A[M,K](bf16) * B(op, fp32 -> bf16 in staging)
// EPI : 0 = bf16 out, 1 = f32 out, 2 = SwiGLU pair (interleaved-16 cols) -> bf16
// BSRC: 1 = fp32 B^T [N,K] | 2 = fp32 B [K,N] (reg micro-transpose; REMAP = w12
//       interleave) | 3 = dual fp32 B^T gate/up interleaved per 16 virtual cols
#define BKK 64

template<int EPI, int BSRC, bool IND, bool REMAP>
__global__ __launch_bounds__(512, 2) void gemm8(const uint16_t* __restrict__ A,
                                                const float* __restrict__ B,
                                                const float* __restrict__ B2,
                                                void* __restrict__ C,
                                                const int* __restrict__ invmap,
                                                const int* __restrict__ counts,
                                                int K, int lda, int ldb, int ldc,
                                                long long strideA, long long strideB,
                                                long long strideC, int grouped,
                                                int nM, int nN) {
  // XCD-chunked decode (grid % 8 == 0), m fastest
  const int per = gridDim.x >> 3;
  const int w = ((int)blockIdx.x & 7) * per + ((int)blockIdx.x >> 3);
  const int mi = w % nM;
  const int q1 = w / nM;
  const int ni = q1 % nN;
  const int e  = q1 / nN;
  int cnt = 1 << 30;
  if (grouped) {
    cnt = counts[e];
    if (mi * 256 >= cnt) return;
  }
  const int bm0 = mi * 256, bn0 = ni * 256;
  const uint16_t* Ab = A + (size_t)e * strideA;
  const float* Bb = B + (size_t)e * strideB;
  __shared__ alignas(16) uint16_t sA[2][256 * 64];
  __shared__ alignas(16) uint16_t sB[2][256 * 64];
  const int tid = threadIdx.x, wid = tid >> 6, lane = tid & 63;
  const int wm = wid >> 2, wn = wid & 3;
  const int l15 = lane & 15, q8 = (lane >> 4) * 8;

  // ---- A-side: 4 global_load_lds pointers (source chunk pre-swizzled) ----
  const uint16_t* apg[4];
#pragma unroll
  for (int h = 0; h < 2; h++)
#pragma unroll
    for (int i = 0; i < 2; i++) {
      int R = h * 128 + i * 64 + (tid >> 3);
      int ar = bm0 + R;
      if constexpr (IND) {
        int cr = ar < cnt ? ar : cnt - 1;
        ar = invmap[e * CAPE + cr];
      }
      apg[h * 2 + i] = Ab + (size_t)ar * lda + (((tid & 7) ^ ((R ^ (R >> 2)) & 7)) * 8);
    }

  // ---- B-side source pointers (per half) ----
  const float* bp[2];
  long long bstep;
  if constexpr (BSRC == 1) {
#pragma unroll
    for (int h = 0; h < 2; h++) {
      int n = bn0 + h * 128 + (tid >> 2);
      bp[h] = Bb + (size_t)n * ldb + (tid & 3) * 16;
    }
    bstep = BKK;
  } else if constexpr (BSRC == 3) {
#pragma unroll
    for (int h = 0; h < 2; h++) {
      int vn = bn0 + h * 128 + (tid >> 2);
      const float* s0 = ((vn & 31) < 16) ? B : B2;
      int pn = (vn >> 5) * 16 + (vn & 15);
      bp[h] = s0 + (size_t)pn * ldb + (tid & 3) * 16;
    }
    bstep = BKK;
  } else {
#pragma unroll
    for (int h = 0; h < 2; h++) {
      int vn0 = bn0 + h * 128 + (tid & 31) * 4;
      int ng0;
      if constexpr (REMAP) {
        int blk = vn0 >> 5, lo = vn0 & 31;
        ng0 = blk * 16 + (lo & 15) + (lo < 16 ? 0 : FF);
      } else {
        ng0 = vn0;
      }
      bp[h] = Bb + (size_t)((tid >> 5) * 4) * ldb + ng0;
    }
    bstep = (long long)BKK * ldb;
  }

  auto stageLoad = [&](int h, f32x4 (&bv)[4]) {
    if constexpr (BSRC == 2) {
#pragma unroll
      for (int j = 0; j < 4; j++) bv[j] = *(const f32x4*)(bp[h] + (size_t)j * ldb);
    } else {
#pragma unroll
      for (int j = 0; j < 4; j++) bv[j] = *(const f32x4*)(bp[h] + 4 * j);
    }
    bp[h] += bstep;
  };
  auto stageWrite = [&](int nb, int h, f32x4 (&bv)[4]) {
    if constexpr (BSRC == 2) {
#pragma unroll
      for (int c = 0; c < 4; c++) {
        int R = h * 128 + (tid & 31) * 4 + c;
        uint2 p;
        p.x = pk_bf16(bv[0][c], bv[1][c]);
        p.y = pk_bf16(bv[2][c], bv[3][c]);
        *(uint2*)(&sB[nb][R * 64 + (((tid >> 5) * 4) ^ swzh(R))]) = p;
      }
    } else {
      int R = h * 128 + (tid >> 2);
      int s = swzh(R);
      uint4 u;
      u.x = pk_bf16(bv[0][0], bv[0][1]); u.y = pk_bf16(bv[0][2], bv[0][3]);
      u.z = pk_bf16(bv[1][0], bv[1][1]); u.w = pk_bf16(bv[1][2], bv[1][3]);
      *(uint4*)(&sB[nb][R * 64 + ((((tid & 3) * 16) + 0) ^ s)]) = u;
      u.x = pk_bf16(bv[2][0], bv[2][1]); u.y = pk_bf16(bv[2][2], bv[2][3]);
      u.z = pk_bf16(bv[3][0], bv[3][1]); u.w = pk_bf16(bv[3][2], bv[3][3]);
      *(uint4*)(&sB[nb][R * 64 + ((((tid & 3) * 16) + 8) ^ s)]) = u;
    }
  };
  auto stageA = [&](int nb, int h) {
#pragma unroll
    for (int i = 0; i < 2; i++) {
      load_lds16(apg[h * 2 + i], &sA[nb][h * 8192 + i * 4096 + tid * 8]);
      apg[h * 2 + i] += BKK;
    }
  };

  f32x4 acc[8][4];
#pragma unroll
  for (int i = 0; i < 8; i++)
#pragma unroll
    for (int j = 0; j < 4; j++) acc[i][j] = (f32x4){0.f, 0.f, 0.f, 0.f};

  auto readA = [&](int buf, int mh, int ks, bf16x8 (&af)[4]) {
#pragma unroll
    for (int f = 0; f < 4; f++) {
      int R = wm * 128 + (mh * 4 + f) * 16 + l15;
      af[f] = *(const bf16x8*)(&sA[buf][R * 64 + ((ks * 32 + q8) ^ swzh(R))]);
    }
  };
  auto readB = [&](int buf, int ks, bf16x8 (&bq)[4]) {
#pragma unroll
    for (int f = 0; f < 4; f++) {
      int R = wn * 64 + f * 16 + l15;
      bq[f] = *(const bf16x8*)(&sB[buf][R * 64 + ((ks * 32 + q8) ^ swzh(R))]);
    }
  };

#define MFMAQ(mh, af, bq)                                                      \
  _Pragma("unroll") for (int f = 0; f < 4; f++)                                \
  _Pragma("unroll") for (int n = 0; n < 4; n++)                                \
    acc[(mh) * 4 + f][n] = __builtin_amdgcn_mfma_f32_16x16x32_bf16(            \
        af[f], bq[n], acc[(mh) * 4 + f][n], 0, 0, 0);

#define PH_GATE()                                                              \
  __builtin_amdgcn_s_barrier();                                                \
  asm volatile("s_waitcnt lgkmcnt(0)" ::: "memory");                           \
  __builtin_amdgcn_sched_barrier(0);                                           \
  __builtin_amdgcn_s_setprio(1);

#define PH_END()                                                               \
  __builtin_amdgcn_s_setprio(0);                                               \
  __builtin_amdgcn_s_barrier();

  // ---- prologue: stage tile 0 into buf 0 ----
  {
    f32x4 bv0[4], bv1[4];
    stageLoad(0, bv0);
    stageLoad(1, bv1);
    stageA(0, 0);
    stageA(0, 1);
    stageWrite(0, 0, bv0);
    stageWrite(0, 1, bv1);
  }
  asm volatile("s_waitcnt vmcnt(0) lgkmcnt(0)" ::: "memory");
  __builtin_amdgcn_sched_barrier(0);
  __builtin_amdgcn_s_barrier();

  const int T = K / BKK;
  for (int t = 0; t < T; t++) {
    const int cur = t & 1, nb = cur ^ 1;
    const bool more = (t + 1 < T);
    bf16x8 bq[4];
    f32x4 bv0[4], bv1[4];
    // ph0: (mh0, ks0) | issue B half0(t+1)
    {
      bf16x8 af[4];
      readA(cur, 0, 0, af);
      readB(cur, 0, bq);
      if (more) stageLoad(0, bv0);
      PH_GATE();
      MFMAQ(0, af, bq);
      PH_END();
    }
    // ph1: (mh1, ks0) | issue B half1(t+1), DMA A half0(t+1)
    {
      bf16x8 af[4];
      readA(cur, 1, 0, af);
      if (more) { stageLoad(1, bv1); stageA(nb, 0); }
      PH_GATE();
      MFMAQ(1, af, bq);
      PH_END();
    }
    // ph2: (mh0, ks1) | cvt+write B half0, DMA A half1(t+1)
    {
      bf16x8 af[4];
      readA(cur, 0, 1, af);
      readB(cur, 1, bq);
      if (more) { stageWrite(nb, 0, bv0); stageA(nb, 1); }
      PH_GATE();
      MFMAQ(0, af, bq);
      PH_END();
    }
    // ph3: (mh1, ks1) | cvt+write B half1; iter-end drain
    {
      bf16x8 af[4];
      readA(cur, 1, 1, af);
      if (more) stageWrite(nb, 1, bv1);
      PH_GATE();
      MFMAQ(1, af, bq);
      __builtin_amdgcn_s_setprio(0);
      asm volatile("s_waitcnt vmcnt(0)" ::: "memory");
      __builtin_amdgcn_sched_barrier(0);
      __builtin_amdgcn_s_barrier();
    }
  }

  // ---- epilogue ----
  const int lr = (lane >> 4) * 4, lc = lane & 15;
  if constexpr (EPI == 2) {
    uint16_t* outp = (uint16_t*)C + (size_t)e * strideC;
#pragma unroll
    for (int mf = 0; mf < 8; mf++) {
#pragma unroll
      for (int fp = 0; fp < 2; fp++) {
        f32x4 g = acc[mf][2 * fp], u = acc[mf][2 * fp + 1];
        int fcol = (bn0 >> 1) + wn * 32 + fp * 16 + lc;
#pragma unroll
        for (int j = 0; j < 4; j++) {
          int r = bm0 + wm * 128 + mf * 16 + lr + j;
          float gv = g[j];
          float sv = (gv / (1.f + expf(-gv))) * u[j];
          outp[(size_t)r * ldc + fcol] = f2bf(sv);
        }
      }
    }
  } else if constexpr (EPI == 1) {
    float* outp = (float*)C + (size_t)e * strideC;
#pragma unroll
    for (int mf = 0; mf < 8; mf++)
#pragma unroll
      for (int nf = 0; nf < 4; nf++) {
        int col = bn0 + wn * 64 + nf * 16 + lc;
#pragma unroll
        for (int j = 0; j < 4; j++) {
          int r = bm0 + wm * 128 + mf * 16 + lr + j;
          outp[(size_t)r * ldc + col] = acc[mf][nf][j];
        }
      }
  } else {
    uint16_t* outp = (uint16_t*)C + (size_t)e * strideC;
#pragma unroll
    for (int mf = 0; mf < 8; mf++)
#pragma unroll
      for (int nf = 0; nf < 4; nf++) {
        int col = bn0 + wn * 64 + nf * 16 + lc;
#pragma unroll
        for (int j = 0; j < 4; j++) {
          int r = bm0 + wm * 128 + mf * 16 + lr + j;
          outp[(size_t)r * ldc + col] = f2bf(acc[mf][nf][j]);
        }
      }
  }
#undef MFMAQ
#undef PH_GATE
#undef PH_END
}

// ---------------- combine ----------------
__global__ __launch_bounds__(256) void combine_kernel(const float* __restrict__ shout,
                                                      const uint16_t* __restrict__ eout,
                                                      const int* __restrict__ dest,
                                                      const uint16_t* __restrict__ gating,
                                                      float* __restrict__ out) {
  const int t = blockIdx.x;
  const int d0 = threadIdx.x * 4;
  float4 sh = *(const float4*)(shout + (size_t)t * DIM + d0);
  float rx = 0.f, ry = 0.f, rz = 0.f, rw = 0.f;
#pragma unroll
  for (int k = 0; k < KSEL; k++) {
    int dp = dest[t * KSEL + k];
    if (dp >= 0) {
      float gw = bf2f(gating[t * KSEL + k]);
      ushort4 ev = *(const ushort4*)(eout + (size_t)dp * DIM + d0);
      rx += gw * bf2f(ev.x);
      ry += gw * bf2f(ev.y);
      rz += gw * bf2f(ev.z);
      rw += gw * bf2f(ev.w);
    }
  }
  float4 o;
  o.x = (sh.x + rx) * 0.5f;
  o.y = (sh.y + ry) * 0.5f;
  o.z = (sh.z + rz) * 0.5f;
  o.w = (sh.w + rw) * 0.5f;
  *(float4*)(out + (size_t)t * DIM + d0) = o;
}

extern "C" void kernel_launch(void* const* d_in, const int* in_sizes, int n_in,
                              void* d_out, int out_size, void* d_ws, size_t ws_size,
                              hipStream_t stream) {
  (void)in_sizes; (void)n_in; (void)out_size; (void)ws_size;
  const float* x   = (const float*)d_in[0];
  const float* rw  = (const float*)d_in[1];
  const float* w12 = (const float*)d_in[2];
  const float* w3  = (const float*)d_in[3];
  const float* gw  = (const float*)d_in[4];
  const float* uw  = (const float*)d_in[5];
  const float* dw  = (const float*)d_in[6];
  float* out = (float*)d_out;

  char* ws = (char*)d_ws;
  size_t off = 0;
  auto alloc = [&](size_t sz) -> void* {
    void* p = ws + off;
    off += (sz + 255) & ~(size_t)255;
    return p;
  };
  uint16_t* HB    = (uint16_t*)alloc((size_t)NTOK * DIM * 2);
  uint16_t* S1    = (uint16_t*)alloc((size_t)NTOK * DFFC * 2);
  uint16_t* ACT   = (uint16_t*)alloc((size_t)NEXP * CAPE * FF * 2);
  uint16_t* EOUT  = (uint16_t*)alloc((size_t)NEXP * CAPE * DIM * 2);
  float* SHOUT    = (float*)alloc((size_t)NTOK * DIM * 4);
  int* TOPKB      = (int*)alloc((size_t)NTOK * KSEL * 4);
  uint16_t* GATING= (uint16_t*)alloc((size_t)NTOK * KSEL * 2);
  int* DEST       = (int*)alloc((size_t)NTOK * KSEL * 4);
  int* INVMAP     = (int*)alloc((size_t)NEXP * CAPE * 4);
  int* COUNTS     = (int*)alloc((size_t)NEXP * 4);
  float* TOKZ     = (float*)alloc((size_t)NTOK * 4);

  // router / dispatch / z-loss (router also emits bf16 x)
  router_kernel<<<NTOK / 16, 256, 0, stream>>>(x, rw, TOPKB, GATING, TOKZ, HB);
  dispatch_kernel<<<NEXP, 64, 0, stream>>>(TOPKB, DEST, INVMAP, COUNTS);
  zred_kernel<<<1, 256, 0, stream>>>(TOKZ, out + (size_t)NTOK * DIM);

  // shared expert: fused gate+up SwiGLU GEMM, then down-proj
  gemm8<2, 3, false, false><<<(NTOK / 256) * (2 * DFFC / 256), 512, 0, stream>>>(
      HB, gw, uw, S1, nullptr, nullptr, DIM, DIM, DIM, DFFC, 0, 0, 0, 0,
      NTOK / 256, 2 * DFFC / 256);
  gemm8<1, 1, false, false><<<(NTOK / 256) * (DIM / 256), 512, 0, stream>>>(
      S1, dw, nullptr, SHOUT, nullptr, nullptr, DFFC, DFFC, DFFC, DIM, 0, 0, 0, 0,
      NTOK / 256, DIM / 256);

  // routed experts (grouped), fp32 K-major weights staged directly
  gemm8<2, 2, true, true><<<(CAPE / 256) * (FF2 / 256) * NEXP, 512, 0, stream>>>(
      HB, w12, nullptr, ACT, INVMAP, COUNTS, DIM, DIM, FF2, FF,
      0, (long long)DIM * FF2, (long long)CAPE * FF, 1, CAPE / 256, FF2 / 256);
  gemm8<0, 2, false, false><<<(CAPE / 256) * (DIM / 256) * NEXP, 512, 0, stream>>>(
      ACT, w3, nullptr, EOUT, nullptr, COUNTS, FF, FF, DIM, DIM,
      (long long)CAPE * FF, (long long)FF * DIM, (long long)CAPE * DIM, 1,
      CAPE / 256, DIM / 256);

  // combine
  combine_kernel<<<NTOK, 256, 0, stream>>>(SHOUT, EOUT, DEST, GATING, out);
}

// Round 6
// 996.637 us; speedup vs baseline: 1.0068x; 1.0068x over previous
//
#include <hip/hip_runtime.h>
#include <stdint.h>
#include <math.h>

#define NTOK 4096
#define DIM  1024
#define NEXP 64
#define KSEL 6
#define FF   1408
#define FF2  2816
#define DFFC 4096
#define CAPE 768

typedef __bf16 bf16x8 __attribute__((ext_vector_type(8)));
typedef float  f32x4  __attribute__((ext_vector_type(4)));

__device__ __forceinline__ float bf2f(uint32_t h) {
  union { uint32_t u; float f; } v; v.u = h << 16; return v.f;
}
__device__ __forceinline__ uint16_t f2bf(float f) {
  union { float f; uint32_t u; } v; v.f = f;
  return (uint16_t)((v.u + 0x7fffu + ((v.u >> 16) & 1u)) >> 16);
}
// packed RNE f32->bf16 pair (low = a, high = b)
__device__ __forceinline__ uint32_t pk_bf16(float a, float b) {
  uint32_t r;
  asm("v_cvt_pk_bf16_f32 %0, %1, %2" : "=v"(r) : "v"(a), "v"(b));
  return r;
}
// LDS XOR swizzle in halves (bits 3-5), proven conflict-free in r3
__device__ __forceinline__ int swzh(int r) { return ((r ^ (r >> 2)) & 7) << 3; }

__device__ __forceinline__ void load_lds16(const void* g, void* l) {
  __builtin_amdgcn_global_load_lds((const __attribute__((address_space(1))) void*)g,
                                   (__attribute__((address_space(3))) void*)l, 16, 0, 0);
}

// ---------------- router: logits, top-6, gating, z partial, bf16 x ----------------
__global__ __launch_bounds__(256) void router_kernel(const float* __restrict__ x,
                                                     const float* __restrict__ rw,
                                                     int* __restrict__ topk,
                                                     uint16_t* __restrict__ gating,
                                                     float* __restrict__ tokz,
                                                     uint16_t* __restrict__ hb) {
  __shared__ float hs[16 * DIM];
  __shared__ float lg[16][NEXP];
  const int tid = threadIdx.x;
  const int t0 = blockIdx.x * 16;
  const float4* xin = (const float4*)(x + (size_t)t0 * DIM);
  float4* hs4 = (float4*)hs;
  for (int i = tid; i < 16 * DIM / 4; i += 256) hs4[i] = xin[i];
  __syncthreads();
  {
    ushort4* hbo = (ushort4*)(hb + (size_t)t0 * DIM);
    for (int i = tid; i < 16 * DIM / 4; i += 256) {
      float4 v = hs4[i];
      ushort4 o;
      o.x = f2bf(v.x); o.y = f2bf(v.y); o.z = f2bf(v.z); o.w = f2bf(v.w);
      hbo[i] = o;
    }
  }
  const int e = tid >> 2, q = tid & 3;
  float part[16];
#pragma unroll
  for (int tt = 0; tt < 16; tt++) part[tt] = 0.f;
  const float4* rw4 = (const float4*)(rw + (size_t)e * DIM + q * 256);
  for (int i = 0; i < 64; i++) {
    float4 w = rw4[i];
#pragma unroll
    for (int tt = 0; tt < 16; tt++) {
      float4 h = *(const float4*)(hs + tt * DIM + q * 256 + i * 4);
      part[tt] += h.x * w.x + h.y * w.y + h.z * w.z + h.w * w.w;
    }
  }
#pragma unroll
  for (int tt = 0; tt < 16; tt++) {
    float v = part[tt];
    v += __shfl_xor(v, 1);
    v += __shfl_xor(v, 2);
    if (q == 0) lg[tt][e] = v;
  }
  __syncthreads();
  const int wid = tid >> 6, lane = tid & 63;
  for (int ti = 0; ti < 4; ti++) {
    int tt = wid * 4 + ti;
    float v = lg[tt][lane];
    float z = v * v;
#pragma unroll
    for (int off = 32; off; off >>= 1) z += __shfl_xor(z, off);
    float bv[KSEL]; int bi[KSEL];
#pragma unroll
    for (int s = 0; s < KSEL; s++) {
      float m = v; int mi = lane;
#pragma unroll
      for (int off = 32; off; off >>= 1) {
        float om = __shfl_xor(m, off); int oi = __shfl_xor(mi, off);
        if (om > m || (om == m && oi < mi)) { m = om; mi = oi; }
      }
      bv[s] = m; bi[s] = mi;
      if (lane == mi) v = -3.0e38f;
    }
    if (lane == 0) {
      int t = t0 + tt;
      tokz[t] = z;
      float mx = bv[0];
      float ex[KSEL], sum = 0.f;
#pragma unroll
      for (int s = 0; s < KSEL; s++) { ex[s] = expf(bv[s] - mx); sum += ex[s]; }
      float inv = 1.f / sum;
#pragma unroll
      for (int s = 0; s < KSEL; s++) {
        topk[t * KSEL + s] = bi[s];
        gating[t * KSEL + s] = f2bf(ex[s] * inv);
      }
    }
  }
}

// ---------------- z_loss reduce ----------------
__global__ __launch_bounds__(256) void zred_kernel(const float* __restrict__ tz,
                                                   float* __restrict__ out) {
  __shared__ float s[256];
  float a = 0.f;
  for (int i = threadIdx.x; i < NTOK; i += 256) a += tz[i];
  s[threadIdx.x] = a; __syncthreads();
  for (int st = 128; st; st >>= 1) {
    if (threadIdx.x < (unsigned)st) s[threadIdx.x] += s[threadIdx.x + st];
    __syncthreads();
  }
  if (threadIdx.x == 0) out[0] = s[0] * (1e-6f / ((float)NTOK * (float)NEXP));
}

// ---------------- dispatch: stable rank within expert ----------------
__global__ __launch_bounds__(64) void dispatch_kernel(const int* __restrict__ topk,
                                                      int* __restrict__ dest,
                                                      int* __restrict__ invmap,
                                                      int* __restrict__ counts) {
  const int e = blockIdx.x;
  const int lane = threadIdx.x;
  int base = 0;
  for (int it = 0; it < (NTOK * KSEL) / 64; it++) {
    int p = it * 64 + lane;
    int ex = topk[p];
    bool m = (ex == e);
    unsigned long long mask = __ballot(m);
    if (m) {
      int intra = base + __popcll(mask & ((1ull << lane) - 1ull));
      if (intra < CAPE) {
        dest[p] = e * CAPE + intra;
        invmap[e * CAPE + intra] = p / KSEL;
      } else {
        dest[p] = -1;
      }
    }
    base += __popcll(mask);
  }
  if (lane == 0) counts[e] = base < CAPE ? base : CAPE;
}

// ---------------- 8-phase BMx256x64 GEMM, 512 thr (2x4 waves) ----------
// C[M,N] = A[M,K](bf16) * B(op, fp32 -> bf16 in staging)
// T4 pipeline: iter t -> ph0/ph1: A-DMA(t+1); ph2/ph3: ds_write B(t+1) + issue
// B-loads(t+2). Iter-end s_waitcnt vmcnt(8) drains A only; 8 B-loads stay in
// flight across the barrier (~4 phases / 800cy of cover).
// EPI : 0 = bf16 out, 1 = f32 out, 2 = SwiGLU pair (interleaved-16 cols) -> bf16
// BSRC: 1 = fp32 B^T [N,K] | 2 = fp32 B [K,N] (reg micro-transpose; REMAP = w12
//       interleave) | 3 = dual fp32 B^T gate/up interleaved per 16 virtual cols
#define BKK 64

template<int EPI, int BSRC, bool IND, bool REMAP, int BM>
__global__ __launch_bounds__(512, 2) void gemm8(const uint16_t* __restrict__ A,
                                                const float* __restrict__ B,
                                                const float* __restrict__ B2,
                                                void* __restrict__ C,
                                                const int* __restrict__ invmap,
                                                const int* __restrict__ counts,
                                                int K, int lda, int ldb, int ldc,
                                                long long strideA, long long strideB,
                                                long long strideC, int grouped,
                                                int nM, int nN) {
  constexpr int MF = BM / 32;     // M fragments per wave
  constexpr int MFH = MF / 2;     // fragments per mh cluster
  constexpr int APH = BM / 128;   // A global_load_lds instrs per half
  // XCD-chunked decode (grid % 8 == 0), m fastest
  const int per = gridDim.x >> 3;
  const int w = ((int)blockIdx.x & 7) * per + ((int)blockIdx.x >> 3);
  const int mi = w % nM;
  const int q1 = w / nM;
  const int ni = q1 % nN;
  const int e  = q1 / nN;
  int cnt = 1 << 30;
  if (grouped) {
    cnt = counts[e];
    if (mi * BM >= cnt) return;
  }
  const int bm0 = mi * BM, bn0 = ni * 256;
  const uint16_t* Ab = A + (size_t)e * strideA;
  const float* Bb = B + (size_t)e * strideB;
  __shared__ alignas(16) uint16_t sA[2][BM * 64];
  __shared__ alignas(16) uint16_t sB[2][256 * 64];
  const int tid = threadIdx.x, wid = tid >> 6, lane = tid & 63;
  const int wm = wid >> 2, wn = wid & 3;
  const int l15 = lane & 15, q8 = (lane >> 4) * 8;

  // ---- A-side: global_load_lds pointers (source chunk pre-swizzled) ----
  const uint16_t* apg[2 * APH];
#pragma unroll
  for (int h = 0; h < 2; h++)
#pragma unroll
    for (int i = 0; i < APH; i++) {
      int R = h * (BM / 2) + i * 64 + (tid >> 3);
      int ar = bm0 + R;
      if constexpr (IND) {
        int cr = ar < cnt ? ar : cnt - 1;
        ar = invmap[e * CAPE + cr];
      }
      apg[h * APH + i] = Ab + (size_t)ar * lda + (((tid & 7) ^ ((R ^ (R >> 2)) & 7)) * 8);
    }

  // ---- B-side source pointers (per N-half of 128) ----
  const float* bp[2];
  long long bstep;
  if constexpr (BSRC == 1) {
#pragma unroll
    for (int h = 0; h < 2; h++) {
      int n = bn0 + h * 128 + (tid >> 2);
      bp[h] = Bb + (size_t)n * ldb + (tid & 3) * 16;
    }
    bstep = BKK;
  } else if constexpr (BSRC == 3) {
#pragma unroll
    for (int h = 0; h < 2; h++) {
      int vn = bn0 + h * 128 + (tid >> 2);
      const float* s0 = ((vn & 31) < 16) ? B : B2;
      int pn = (vn >> 5) * 16 + (vn & 15);
      bp[h] = s0 + (size_t)pn * ldb + (tid & 3) * 16;
    }
    bstep = BKK;
  } else {
#pragma unroll
    for (int h = 0; h < 2; h++) {
      int vn0 = bn0 + h * 128 + (tid & 31) * 4;
      int ng0;
      if constexpr (REMAP) {
        int blk = vn0 >> 5, lo = vn0 & 31;
        ng0 = blk * 16 + (lo & 15) + (lo < 16 ? 0 : FF);
      } else {
        ng0 = vn0;
      }
      bp[h] = Bb + (size_t)((tid >> 5) * 4) * ldb + ng0;
    }
    bstep = (long long)BKK * ldb;
  }

  auto loadB = [&](int h, f32x4 (&bv)[4]) {
    if constexpr (BSRC == 2) {
#pragma unroll
      for (int j = 0; j < 4; j++) bv[j] = *(const f32x4*)(bp[h] + (size_t)j * ldb);
    } else {
#pragma unroll
      for (int j = 0; j < 4; j++) bv[j] = *(const f32x4*)(bp[h] + 4 * j);
    }
    bp[h] += bstep;
  };
  auto writeB = [&](int nb, int h, f32x4 (&bv)[4]) {
    if constexpr (BSRC == 2) {
#pragma unroll
      for (int c = 0; c < 4; c++) {
        int R = h * 128 + (tid & 31) * 4 + c;
        uint2 p;
        p.x = pk_bf16(bv[0][c], bv[1][c]);
        p.y = pk_bf16(bv[2][c], bv[3][c]);
        *(uint2*)(&sB[nb][R * 64 + (((tid >> 5) * 4) ^ swzh(R))]) = p;
      }
    } else {
      int R = h * 128 + (tid >> 2);
      int s = swzh(R);
      uint4 u;
      u.x = pk_bf16(bv[0][0], bv[0][1]); u.y = pk_bf16(bv[0][2], bv[0][3]);
      u.z = pk_bf16(bv[1][0], bv[1][1]); u.w = pk_bf16(bv[1][2], bv[1][3]);
      *(uint4*)(&sB[nb][R * 64 + ((((tid & 3) * 16) + 0) ^ s)]) = u;
      u.x = pk_bf16(bv[2][0], bv[2][1]); u.y = pk_bf16(bv[2][2], bv[2][3]);
      u.z = pk_bf16(bv[3][0], bv[3][1]); u.w = pk_bf16(bv[3][2], bv[3][3]);
      *(uint4*)(&sB[nb][R * 64 + ((((tid & 3) * 16) + 8) ^ s)]) = u;
    }
  };
  auto stageA = [&](int nb, int h) {
#pragma unroll
    for (int i = 0; i < APH; i++) {
      load_lds16(apg[h * APH + i], &sA[nb][h * (BM / 2) * 64 + i * 4096 + tid * 8]);
      apg[h * APH + i] += BKK;
    }
  };

  f32x4 acc[MF][4];
#pragma unroll
  for (int i = 0; i < MF; i++)
#pragma unroll
    for (int j = 0; j < 4; j++) acc[i][j] = (f32x4){0.f, 0.f, 0.f, 0.f};

  auto readA = [&](int buf, int mh, int ks, bf16x8 (&af)[MFH]) {
#pragma unroll
    for (int f = 0; f < MFH; f++) {
      int R = wm * (BM / 2) + (mh * MFH + f) * 16 + l15;
      af[f] = *(const bf16x8*)(&sA[buf][R * 64 + ((ks * 32 + q8) ^ swzh(R))]);
    }
  };
  auto readB = [&](int buf, int ks, bf16x8 (&bq)[4]) {
#pragma unroll
    for (int f = 0; f < 4; f++) {
      int R = wn * 64 + f * 16 + l15;
      bq[f] = *(const bf16x8*)(&sB[buf][R * 64 + ((ks * 32 + q8) ^ swzh(R))]);
    }
  };

#define MFMAQ(mh)                                                              \
  _Pragma("unroll") for (int f = 0; f < MFH; f++)                              \
  _Pragma("unroll") for (int n = 0; n < 4; n++)                                \
    acc[(mh) * MFH + f][n] = __builtin_amdgcn_mfma_f32_16x16x32_bf16(          \
        af[f], bq[n], acc[(mh) * MFH + f][n], 0, 0, 0);

#define PH_GATE()                                                              \
  __builtin_amdgcn_s_barrier();                                                \
  asm volatile("s_waitcnt lgkmcnt(0)" ::: "memory");                           \
  __builtin_amdgcn_sched_barrier(0);                                           \
  __builtin_amdgcn_s_setprio(1);

#define PH_END()                                                               \
  __builtin_amdgcn_s_setprio(0);                                               \
  __builtin_amdgcn_s_barrier();

  f32x4 bvh0[4], bvh1[4];
  // ---- prologue: stage tile0 into buf0, preload B(t1) regs ----
  loadB(0, bvh0);
  loadB(1, bvh1);
  stageA(0, 0);
  stageA(0, 1);
  writeB(0, 0, bvh0);   // auto vmcnt wait drains B(t0)
  writeB(0, 1, bvh1);
  loadB(0, bvh0);       // B(t1) in flight across the barrier
  loadB(1, bvh1);
  asm volatile("s_waitcnt vmcnt(8) lgkmcnt(0)" ::: "memory");  // drain A(t0), keep B(t1)
  __builtin_amdgcn_sched_barrier(0);
  __builtin_amdgcn_s_barrier();

  const int T = K / BKK;  // all K here are multiples of 128 -> T even, T >= 2
  for (int t = 0; t < T; t++) {
    const int cur = t & 1, nb = cur ^ 1;
    const bool more1 = (t + 1 < T);
    const bool more2 = (t + 2 < T);
    bf16x8 af[MFH], bq[4];
    // ph0: MFMA(mh0,ks0) | A-DMA(t+1) half0
    readA(cur, 0, 0, af);
    readB(cur, 0, bq);
    if (more1) stageA(nb, 0);
    PH_GATE();
    MFMAQ(0);
    PH_END();
    // ph1: MFMA(mh1,ks0) | A-DMA(t+1) half1
    readA(cur, 1, 0, af);
    if (more1) stageA(nb, 1);
    PH_GATE();
    MFMAQ(1);
    PH_END();
    // ph2: MFMA(mh0,ks1) | cvt+ds_write B(t+1) h0, issue B-loads(t+2) h0
    readA(cur, 0, 1, af);
    readB(cur, 1, bq);
    if (more1) writeB(nb, 0, bvh0);
    if (more2) loadB(0, bvh0);
    PH_GATE();
    MFMAQ(0);
    PH_END();
    // ph3: MFMA(mh1,ks1) | cvt+ds_write B(t+1) h1, issue B-loads(t+2) h1
    readA(cur, 1, 1, af);
    if (more1) writeB(nb, 1, bvh1);
    if (more2) loadB(1, bvh1);
    PH_GATE();
    MFMAQ(1);
    __builtin_amdgcn_s_setprio(0);
    if (more2) {
      asm volatile("s_waitcnt vmcnt(8)" ::: "memory");  // drain A(t+1), keep B(t+2)
    } else {
      asm volatile("s_waitcnt vmcnt(0)" ::: "memory");  // tail: drain everything
    }
    __builtin_amdgcn_sched_barrier(0);
    __builtin_amdgcn_s_barrier();
  }

  // ---- epilogue ----
  const int lr = (lane >> 4) * 4, lc = lane & 15;
  if constexpr (EPI == 2) {
    uint16_t* outp = (uint16_t*)C + (size_t)e * strideC;
#pragma unroll
    for (int mf = 0; mf < MF; mf++) {
#pragma unroll
      for (int fp = 0; fp < 2; fp++) {
        f32x4 g = acc[mf][2 * fp], u = acc[mf][2 * fp + 1];
        int fcol = (bn0 >> 1) + wn * 32 + fp * 16 + lc;
#pragma unroll
        for (int j = 0; j < 4; j++) {
          int r = bm0 + wm * (BM / 2) + mf * 16 + lr + j;
          float gv = g[j];
          float sv = (gv / (1.f + expf(-gv))) * u[j];
          outp[(size_t)r * ldc + fcol] = f2bf(sv);
        }
      }
    }
  } else if constexpr (EPI == 1) {
    float* outp = (float*)C + (size_t)e * strideC;
#pragma unroll
    for (int mf = 0; mf < MF; mf++)
#pragma unroll
      for (int nf = 0; nf < 4; nf++) {
        int col = bn0 + wn * 64 + nf * 16 + lc;
#pragma unroll
        for (int j = 0; j < 4; j++) {
          int r = bm0 + wm * (BM / 2) + mf * 16 + lr + j;
          outp[(size_t)r * ldc + col] = acc[mf][nf][j];
        }
      }
  } else {
    uint16_t* outp = (uint16_t*)C + (size_t)e * strideC;
#pragma unroll
    for (int mf = 0; mf < MF; mf++)
#pragma unroll
      for (int nf = 0; nf < 4; nf++) {
        int col = bn0 + wn * 64 + nf * 16 + lc;
#pragma unroll
        for (int j = 0; j < 4; j++) {
          int r = bm0 + wm * (BM / 2) + mf * 16 + lr + j;
          outp[(size_t)r * ldc + col] = f2bf(acc[mf][nf][j]);
        }
      }
  }
#undef MFMAQ
#undef PH_GATE
#undef PH_END
}

// ---------------- combine ----------------
__global__ __launch_bounds__(256) void combine_kernel(const float* __restrict__ shout,
                                                      const uint16_t* __restrict__ eout,
                                                      const int* __restrict__ dest,
                                                      const uint16_t* __restrict__ gating,
                                                      float* __restrict__ out) {
  const int t = blockIdx.x;
  const int d0 = threadIdx.x * 4;
  float4 sh = *(const float4*)(shout + (size_t)t * DIM + d0);
  float rx = 0.f, ry = 0.f, rz = 0.f, rw = 0.f;
#pragma unroll
  for (int k = 0; k < KSEL; k++) {
    int dp = dest[t * KSEL + k];
    if (dp >= 0) {
      float gw = bf2f(gating[t * KSEL + k]);
      ushort4 ev = *(const ushort4*)(eout + (size_t)dp * DIM + d0);
      rx += gw * bf2f(ev.x);
      ry += gw * bf2f(ev.y);
      rz += gw * bf2f(ev.z);
      rw += gw * bf2f(ev.w);
    }
  }
  float4 o;
  o.x = (sh.x + rx) * 0.5f;
  o.y = (sh.y + ry) * 0.5f;
  o.z = (sh.z + rz) * 0.5f;
  o.w = (sh.w + rw) * 0.5f;
  *(float4*)(out + (size_t)t * DIM + d0) = o;
}

extern "C" void kernel_launch(void* const* d_in, const int* in_sizes, int n_in,
                              void* d_out, int out_size, void* d_ws, size_t ws_size,
                              hipStream_t stream) {
  (void)in_sizes; (void)n_in; (void)out_size; (void)ws_size;
  const float* x   = (const float*)d_in[0];
  const float* rw  = (const float*)d_in[1];
  const float* w12 = (const float*)d_in[2];
  const float* w3  = (const float*)d_in[3];
  const float* gw  = (const float*)d_in[4];
  const float* uw  = (const float*)d_in[5];
  const float* dw  = (const float*)d_in[6];
  float* out = (float*)d_out;

  char* ws = (char*)d_ws;
  size_t off = 0;
  auto alloc = [&](size_t sz) -> void* {
    void* p = ws + off;
    off += (sz + 255) & ~(size_t)255;
    return p;
  };
  uint16_t* HB    = (uint16_t*)alloc((size_t)NTOK * DIM * 2);
  uint16_t* S1    = (uint16_t*)alloc((size_t)NTOK * DFFC * 2);
  uint16_t* ACT   = (uint16_t*)alloc((size_t)NEXP * CAPE * FF * 2);
  uint16_t* EOUT  = (uint16_t*)alloc((size_t)NEXP * CAPE * DIM * 2);
  float* SHOUT    = (float*)alloc((size_t)NTOK * DIM * 4);
  int* TOPKB      = (int*)alloc((size_t)NTOK * KSEL * 4);
  uint16_t* GATING= (uint16_t*)alloc((size_t)NTOK * KSEL * 2);
  int* DEST       = (int*)alloc((size_t)NTOK * KSEL * 4);
  int* INVMAP     = (int*)alloc((size_t)NEXP * CAPE * 4);
  int* COUNTS     = (int*)alloc((size_t)NEXP * 4);
  float* TOKZ     = (float*)alloc((size_t)NTOK * 4);

  // router / dispatch / z-loss (router also emits bf16 x)
  router_kernel<<<NTOK / 16, 256, 0, stream>>>(x, rw, TOPKB, GATING, TOKZ, HB);
  dispatch_kernel<<<NEXP, 64, 0, stream>>>(TOPKB, DEST, INVMAP, COUNTS);
  zred_kernel<<<1, 256, 0, stream>>>(TOKZ, out + (size_t)NTOK * DIM);

  // shared expert: fused gate+up SwiGLU GEMM (BM=256), then down-proj (BM=128)
  gemm8<2, 3, false, false, 256><<<(NTOK / 256) * (2 * DFFC / 256), 512, 0, stream>>>(
      HB, gw, uw, S1, nullptr, nullptr, DIM, DIM, DIM, DFFC, 0, 0, 0, 0,
      NTOK / 256, 2 * DFFC / 256);
  gemm8<1, 1, false, false, 128><<<(NTOK / 128) * (DIM / 256), 512, 0, stream>>>(
      S1, dw, nullptr, SHOUT, nullptr, nullptr, DFFC, DFFC, DFFC, DIM, 0, 0, 0, 0,
      NTOK / 128, DIM / 256);

  // routed experts (grouped, BM=128 to cut cnt-padding), fp32 K-major weights
  gemm8<2, 2, true, true, 128><<<(CAPE / 128) * (FF2 / 256) * NEXP, 512, 0, stream>>>(
      HB, w12, nullptr, ACT, INVMAP, COUNTS, DIM, DIM, FF2, FF,
      0, (long long)DIM * FF2, (long long)CAPE * FF, 1, CAPE / 128, FF2 / 256);
  gemm8<0, 2, false, false, 128><<<(CAPE / 128) * (DIM / 256) * NEXP, 512, 0, stream>>>(
      ACT, w3, nullptr, EOUT, nullptr, COUNTS, FF, FF, DIM, DIM,
      (long long)CAPE * FF, (long long)FF * DIM, (long long)CAPE * DIM, 1,
      CAPE / 128, DIM / 256);

  // combine
  combine_kernel<<<NTOK, 256, 0, stream>>>(SHOUT, EOUT, DEST, GATING, out);
}

// Round 7
// 919.979 us; speedup vs baseline: 1.0907x; 1.0833x over previous
//
#include <hip/hip_runtime.h>
#include <stdint.h>
#include <math.h>

#define NTOK 4096
#define DIM  1024
#define NEXP 64
#define KSEL 6
#define FF   1408
#define FF2  2816
#define DFFC 4096
#define CAPE 768

typedef __bf16 bf16x8 __attribute__((ext_vector_type(8)));
typedef float  f32x4  __attribute__((ext_vector_type(4)));

__device__ __forceinline__ float bf2f(uint32_t h) {
  union { uint32_t u; float f; } v; v.u = h << 16; return v.f;
}
__device__ __forceinline__ uint16_t f2bf(float f) {
  union { float f; uint32_t u; } v; v.f = f;
  return (uint16_t)((v.u + 0x7fffu + ((v.u >> 16) & 1u)) >> 16);
}
// packed RNE f32->bf16 pair (low = a, high = b)
__device__ __forceinline__ uint32_t pk_bf16(float a, float b) {
  uint32_t r;
  asm("v_cvt_pk_bf16_f32 %0, %1, %2" : "=v"(r) : "v"(a), "v"(b));
  return r;
}
// LDS XOR swizzle in halves (bits 3-5), proven conflict-free in r3
__device__ __forceinline__ int swzh(int r) { return ((r ^ (r >> 2)) & 7) << 3; }

__device__ __forceinline__ void load_lds16(const void* g, void* l) {
  __builtin_amdgcn_global_load_lds((const __attribute__((address_space(1))) void*)g,
                                   (__attribute__((address_space(3))) void*)l, 16, 0, 0);
}

// ---------------- router: logits, top-6, gating, z partial, bf16 x ----------------
__global__ __launch_bounds__(256) void router_kernel(const float* __restrict__ x,
                                                     const float* __restrict__ rw,
                                                     int* __restrict__ topk,
                                                     uint16_t* __restrict__ gating,
                                                     float* __restrict__ tokz,
                                                     uint16_t* __restrict__ hb) {
  __shared__ float hs[16 * DIM];
  __shared__ float lg[16][NEXP];
  const int tid = threadIdx.x;
  const int t0 = blockIdx.x * 16;
  const float4* xin = (const float4*)(x + (size_t)t0 * DIM);
  float4* hs4 = (float4*)hs;
  for (int i = tid; i < 16 * DIM / 4; i += 256) hs4[i] = xin[i];
  __syncthreads();
  {
    ushort4* hbo = (ushort4*)(hb + (size_t)t0 * DIM);
    for (int i = tid; i < 16 * DIM / 4; i += 256) {
      float4 v = hs4[i];
      ushort4 o;
      o.x = f2bf(v.x); o.y = f2bf(v.y); o.z = f2bf(v.z); o.w = f2bf(v.w);
      hbo[i] = o;
    }
  }
  const int e = tid >> 2, q = tid & 3;
  float part[16];
#pragma unroll
  for (int tt = 0; tt < 16; tt++) part[tt] = 0.f;
  const float4* rw4 = (const float4*)(rw + (size_t)e * DIM + q * 256);
  for (int i = 0; i < 64; i++) {
    float4 w = rw4[i];
#pragma unroll
    for (int tt = 0; tt < 16; tt++) {
      float4 h = *(const float4*)(hs + tt * DIM + q * 256 + i * 4);
      part[tt] += h.x * w.x + h.y * w.y + h.z * w.z + h.w * w.w;
    }
  }
#pragma unroll
  for (int tt = 0; tt < 16; tt++) {
    float v = part[tt];
    v += __shfl_xor(v, 1);
    v += __shfl_xor(v, 2);
    if (q == 0) lg[tt][e] = v;
  }
  __syncthreads();
  const int wid = tid >> 6, lane = tid & 63;
  for (int ti = 0; ti < 4; ti++) {
    int tt = wid * 4 + ti;
    float v = lg[tt][lane];
    float z = v * v;
#pragma unroll
    for (int off = 32; off; off >>= 1) z += __shfl_xor(z, off);
    float bv[KSEL]; int bi[KSEL];
#pragma unroll
    for (int s = 0; s < KSEL; s++) {
      float m = v; int mi = lane;
#pragma unroll
      for (int off = 32; off; off >>= 1) {
        float om = __shfl_xor(m, off); int oi = __shfl_xor(mi, off);
        if (om > m || (om == m && oi < mi)) { m = om; mi = oi; }
      }
      bv[s] = m; bi[s] = mi;
      if (lane == mi) v = -3.0e38f;
    }
    if (lane == 0) {
      int t = t0 + tt;
      tokz[t] = z;
      float mx = bv[0];
      float ex[KSEL], sum = 0.f;
#pragma unroll
      for (int s = 0; s < KSEL; s++) { ex[s] = expf(bv[s] - mx); sum += ex[s]; }
      float inv = 1.f / sum;
#pragma unroll
      for (int s = 0; s < KSEL; s++) {
        topk[t * KSEL + s] = bi[s];
        gating[t * KSEL + s] = f2bf(ex[s] * inv);
      }
    }
  }
}

// ---------------- z_loss reduce ----------------
__global__ __launch_bounds__(256) void zred_kernel(const float* __restrict__ tz,
                                                   float* __restrict__ out) {
  __shared__ float s[256];
  float a = 0.f;
  for (int i = threadIdx.x; i < NTOK; i += 256) a += tz[i];
  s[threadIdx.x] = a; __syncthreads();
  for (int st = 128; st; st >>= 1) {
    if (threadIdx.x < (unsigned)st) s[threadIdx.x] += s[threadIdx.x + st];
    __syncthreads();
  }
  if (threadIdx.x == 0) out[0] = s[0] * (1e-6f / ((float)NTOK * (float)NEXP));
}

// ---------------- dispatch: stable rank within expert ----------------
__global__ __launch_bounds__(64) void dispatch_kernel(const int* __restrict__ topk,
                                                      int* __restrict__ dest,
                                                      int* __restrict__ invmap,
                                                      int* __restrict__ counts) {
  const int e = blockIdx.x;
  const int lane = threadIdx.x;
  int base = 0;
  for (int it = 0; it < (NTOK * KSEL) / 64; it++) {
    int p = it * 64 + lane;
    int ex = topk[p];
    bool m = (ex == e);
    unsigned long long mask = __ballot(m);
    if (m) {
      int intra = base + __popcll(mask & ((1ull << lane) - 1ull));
      if (intra < CAPE) {
        dest[p] = e * CAPE + intra;
        invmap[e * CAPE + intra] = p / KSEL;
      } else {
        dest[p] = -1;
      }
    }
    base += __popcll(mask);
  }
  if (lane == 0) counts[e] = base < CAPE ? base : CAPE;
}

// ---------------- 8-phase 256x256x64 GEMM, 512 thr (2x4 waves), 128 KiB LDS ----------
// C[M,N] = A[M,K](bf16) * B(op, fp32 -> bf16 in staging)
// Per phase: {ds_reads first, ds_writes/vmem issue after} -> barrier ->
// counted lgkmcnt (leave writes in flight) -> setprio -> 16 MFMA -> barrier.
// Iter-end: vmcnt(8) (keep 8 B-loads of t+2 in flight) + lgkmcnt(0) (publish
// ds_writes of t+1 before buffers swap).
// EPI : 0 = bf16 out, 1 = f32 out, 2 = SwiGLU pair (interleaved-16 cols) -> bf16
// BSRC: 1 = fp32 B^T [N,K] | 2 = fp32 B [K,N] (reg micro-transpose; REMAP = w12
//       interleave) | 3 = dual fp32 B^T gate/up interleaved per 16 virtual cols
#define BKK 64
#define BM 256

template<int EPI, int BSRC, bool IND, bool REMAP>
__global__ __launch_bounds__(512, 2) void gemm8(const uint16_t* __restrict__ A,
                                                const float* __restrict__ B,
                                                const float* __restrict__ B2,
                                                void* __restrict__ C,
                                                const int* __restrict__ invmap,
                                                const int* __restrict__ counts,
                                                int K, int lda, int ldb, int ldc,
                                                long long strideA, long long strideB,
                                                long long strideC, int grouped,
                                                int nM, int nN) {
  // XCD-chunked decode (grid % 8 == 0), m fastest
  const int per = gridDim.x >> 3;
  const int w = ((int)blockIdx.x & 7) * per + ((int)blockIdx.x >> 3);
  const int mi = w % nM;
  const int q1 = w / nM;
  const int ni = q1 % nN;
  const int e  = q1 / nN;
  int cnt = 1 << 30;
  if (grouped) {
    cnt = counts[e];
    if (mi * BM >= cnt) return;
  }
  const int bm0 = mi * BM, bn0 = ni * 256;
  const uint16_t* Ab = A + (size_t)e * strideA;
  const float* Bb = B + (size_t)e * strideB;
  __shared__ alignas(16) uint16_t sA[2][BM * 64];
  __shared__ alignas(16) uint16_t sB[2][256 * 64];
  const int tid = threadIdx.x, wid = tid >> 6, lane = tid & 63;
  const int wm = wid >> 2, wn = wid & 3;
  const int l15 = lane & 15, q8 = (lane >> 4) * 8;

  // ---- A-side: 4 global_load_lds pointers (source chunk pre-swizzled) ----
  const uint16_t* apg[4];
#pragma unroll
  for (int h = 0; h < 2; h++)
#pragma unroll
    for (int i = 0; i < 2; i++) {
      int R = h * 128 + i * 64 + (tid >> 3);
      int ar = bm0 + R;
      if constexpr (IND) {
        int cr = ar < cnt ? ar : cnt - 1;
        ar = invmap[e * CAPE + cr];
      }
      apg[h * 2 + i] = Ab + (size_t)ar * lda + (((tid & 7) ^ ((R ^ (R >> 2)) & 7)) * 8);
    }

  // ---- B-side source pointers (per N-half of 128) ----
  const float* bp[2];
  long long bstep;
  if constexpr (BSRC == 1) {
#pragma unroll
    for (int h = 0; h < 2; h++) {
      int n = bn0 + h * 128 + (tid >> 2);
      bp[h] = Bb + (size_t)n * ldb + (tid & 3) * 16;
    }
    bstep = BKK;
  } else if constexpr (BSRC == 3) {
#pragma unroll
    for (int h = 0; h < 2; h++) {
      int vn = bn0 + h * 128 + (tid >> 2);
      const float* s0 = ((vn & 31) < 16) ? B : B2;
      int pn = (vn >> 5) * 16 + (vn & 15);
      bp[h] = s0 + (size_t)pn * ldb + (tid & 3) * 16;
    }
    bstep = BKK;
  } else {
#pragma unroll
    for (int h = 0; h < 2; h++) {
      int vn0 = bn0 + h * 128 + (tid & 31) * 4;
      int ng0;
      if constexpr (REMAP) {
        int blk = vn0 >> 5, lo = vn0 & 31;
        ng0 = blk * 16 + (lo & 15) + (lo < 16 ? 0 : FF);
      } else {
        ng0 = vn0;
      }
      bp[h] = Bb + (size_t)((tid >> 5) * 4) * ldb + ng0;
    }
    bstep = (long long)BKK * ldb;
  }

  auto loadB = [&](int h, f32x4 (&bv)[4]) {
    if constexpr (BSRC == 2) {
#pragma unroll
      for (int j = 0; j < 4; j++) bv[j] = *(const f32x4*)(bp[h] + (size_t)j * ldb);
    } else {
#pragma unroll
      for (int j = 0; j < 4; j++) bv[j] = *(const f32x4*)(bp[h] + 4 * j);
    }
    bp[h] += bstep;
  };
  auto writeB = [&](int nb, int h, f32x4 (&bv)[4]) {
    if constexpr (BSRC == 2) {
#pragma unroll
      for (int c = 0; c < 4; c++) {
        int R = h * 128 + (tid & 31) * 4 + c;
        uint2 p;
        p.x = pk_bf16(bv[0][c], bv[1][c]);
        p.y = pk_bf16(bv[2][c], bv[3][c]);
        *(uint2*)(&sB[nb][R * 64 + (((tid >> 5) * 4) ^ swzh(R))]) = p;
      }
    } else {
      int R = h * 128 + (tid >> 2);
      int s = swzh(R);
      uint4 u;
      u.x = pk_bf16(bv[0][0], bv[0][1]); u.y = pk_bf16(bv[0][2], bv[0][3]);
      u.z = pk_bf16(bv[1][0], bv[1][1]); u.w = pk_bf16(bv[1][2], bv[1][3]);
      *(uint4*)(&sB[nb][R * 64 + ((((tid & 3) * 16) + 0) ^ s)]) = u;
      u.x = pk_bf16(bv[2][0], bv[2][1]); u.y = pk_bf16(bv[2][2], bv[2][3]);
      u.z = pk_bf16(bv[3][0], bv[3][1]); u.w = pk_bf16(bv[3][2], bv[3][3]);
      *(uint4*)(&sB[nb][R * 64 + ((((tid & 3) * 16) + 8) ^ s)]) = u;
    }
  };
  auto stageA = [&](int nb, int h) {
#pragma unroll
    for (int i = 0; i < 2; i++) {
      load_lds16(apg[h * 2 + i], &sA[nb][h * 8192 + i * 4096 + tid * 8]);
      apg[h * 2 + i] += BKK;
    }
  };

  f32x4 acc[8][4];
#pragma unroll
  for (int i = 0; i < 8; i++)
#pragma unroll
    for (int j = 0; j < 4; j++) acc[i][j] = (f32x4){0.f, 0.f, 0.f, 0.f};

  auto readA = [&](int buf, int mh, int ks, bf16x8 (&af)[4]) {
#pragma unroll
    for (int f = 0; f < 4; f++) {
      int R = wm * 128 + (mh * 4 + f) * 16 + l15;
      af[f] = *(const bf16x8*)(&sA[buf][R * 64 + ((ks * 32 + q8) ^ swzh(R))]);
    }
  };
  auto readB = [&](int buf, int ks, bf16x8 (&bq)[4]) {
#pragma unroll
    for (int f = 0; f < 4; f++) {
      int R = wn * 64 + f * 16 + l15;
      bq[f] = *(const bf16x8*)(&sB[buf][R * 64 + ((ks * 32 + q8) ^ swzh(R))]);
    }
  };

#define MFMAQ(mh)                                                              \
  _Pragma("unroll") for (int f = 0; f < 4; f++)                                \
  _Pragma("unroll") for (int n = 0; n < 4; n++)                                \
    acc[(mh) * 4 + f][n] = __builtin_amdgcn_mfma_f32_16x16x32_bf16(            \
        af[f], bq[n], acc[(mh) * 4 + f][n], 0, 0, 0);

// gate with full lgkm drain (phases with no ds_writes in flight)
#define GATE0()                                                                \
  __builtin_amdgcn_s_barrier();                                                \
  asm volatile("s_waitcnt lgkmcnt(0)" ::: "memory");                           \
  __builtin_amdgcn_sched_barrier(0);                                           \
  __builtin_amdgcn_s_setprio(1);

// gate leaving this phase's ds_writes (issued AFTER the reads) in flight
#define GATEW()                                                                \
  __builtin_amdgcn_s_barrier();                                                \
  if constexpr (BSRC == 2) {                                                   \
    asm volatile("s_waitcnt lgkmcnt(4)" ::: "memory");                         \
  } else {                                                                     \
    asm volatile("s_waitcnt lgkmcnt(2)" ::: "memory");                         \
  }                                                                            \
  __builtin_amdgcn_sched_barrier(0);                                           \
  __builtin_amdgcn_s_setprio(1);

#define PH_END()                                                               \
  __builtin_amdgcn_s_setprio(0);                                               \
  __builtin_amdgcn_s_barrier();

  f32x4 bvh0[4], bvh1[4];
  // ---- prologue: stage tile0 into buf0, preload B(t1) regs ----
  loadB(0, bvh0);
  loadB(1, bvh1);
  stageA(0, 0);
  stageA(0, 1);
  writeB(0, 0, bvh0);   // auto vmcnt wait drains B(t0)
  writeB(0, 1, bvh1);
  loadB(0, bvh0);       // B(t1) in flight across the barrier
  loadB(1, bvh1);
  asm volatile("s_waitcnt vmcnt(8) lgkmcnt(0)" ::: "memory");  // drain A(t0)+writes, keep B(t1)
  __builtin_amdgcn_sched_barrier(0);
  __builtin_amdgcn_s_barrier();

  const int T = K / BKK;  // all K here are multiples of 128 -> T even, T >= 2
  for (int t = 0; t < T; t++) {
    const int cur = t & 1, nb = cur ^ 1;
    const bool more1 = (t + 1 < T);
    const bool more2 = (t + 2 < T);
    bf16x8 af[4], bq[4];
    // ph0: MFMA(mh0,ks0) | A-DMA(t+1) half0
    readA(cur, 0, 0, af);
    readB(cur, 0, bq);
    if (more1) stageA(nb, 0);
    GATE0();
    MFMAQ(0);
    PH_END();
    // ph1: MFMA(mh1,ks0) | A-DMA(t+1) half1
    readA(cur, 1, 0, af);
    if (more1) stageA(nb, 1);
    GATE0();
    MFMAQ(1);
    PH_END();
    // ph2: MFMA(mh0,ks1) | cvt+ds_write B(t+1) h0 (left in flight), B-loads(t+2) h0
    readA(cur, 0, 1, af);
    readB(cur, 1, bq);
    if (more1) writeB(nb, 0, bvh0);
    if (more2) loadB(0, bvh0);
    if (more1) { GATEW(); } else { GATE0(); }
    MFMAQ(0);
    PH_END();
    // ph3: MFMA(mh1,ks1) | cvt+ds_write B(t+1) h1, B-loads(t+2) h1; iter-end drain
    readA(cur, 1, 1, af);
    if (more1) writeB(nb, 1, bvh1);
    if (more2) loadB(1, bvh1);
    if (more1) { GATEW(); } else { GATE0(); }
    MFMAQ(1);
    __builtin_amdgcn_s_setprio(0);
    if (more2) {
      // queue: [A-DMA x4 (oldest), B(t+2) x8] -> drain A + writes, keep B
      asm volatile("s_waitcnt vmcnt(8) lgkmcnt(0)" ::: "memory");
    } else {
      asm volatile("s_waitcnt vmcnt(0) lgkmcnt(0)" ::: "memory");
    }
    __builtin_amdgcn_sched_barrier(0);
    __builtin_amdgcn_s_barrier();
  }

  // ---- epilogue ----
  const int lr = (lane >> 4) * 4, lc = lane & 15;
  if constexpr (EPI == 2) {
    uint16_t* outp = (uint16_t*)C + (size_t)e * strideC;
#pragma unroll
    for (int mf = 0; mf < 8; mf++) {
#pragma unroll
      for (int fp = 0; fp < 2; fp++) {
        f32x4 g = acc[mf][2 * fp], u = acc[mf][2 * fp + 1];
        int fcol = (bn0 >> 1) + wn * 32 + fp * 16 + lc;
#pragma unroll
        for (int j = 0; j < 4; j++) {
          int r = bm0 + wm * 128 + mf * 16 + lr + j;
          float gv = g[j];
          float sv = (gv / (1.f + expf(-gv))) * u[j];
          outp[(size_t)r * ldc + fcol] = f2bf(sv);
        }
      }
    }
  } else if constexpr (EPI == 1) {
    float* outp = (float*)C + (size_t)e * strideC;
#pragma unroll
    for (int mf = 0; mf < 8; mf++)
#pragma unroll
      for (int nf = 0; nf < 4; nf++) {
        int col = bn0 + wn * 64 + nf * 16 + lc;
#pragma unroll
        for (int j = 0; j < 4; j++) {
          int r = bm0 + wm * 128 + mf * 16 + lr + j;
          outp[(size_t)r * ldc + col] = acc[mf][nf][j];
        }
      }
  } else {
    uint16_t* outp = (uint16_t*)C + (size_t)e * strideC;
#pragma unroll
    for (int mf = 0; mf < 8; mf++)
#pragma unroll
      for (int nf = 0; nf < 4; nf++) {
        int col = bn0 + wn * 64 + nf * 16 + lc;
#pragma unroll
        for (int j = 0; j < 4; j++) {
          int r = bm0 + wm * 128 + mf * 16 + lr + j;
          outp[(size_t)r * ldc + col] = f2bf(acc[mf][nf][j]);
        }
      }
  }
#undef MFMAQ
#undef GATE0
#undef GATEW
#undef PH_END
}

// ---------------- combine ----------------
__global__ __launch_bounds__(256) void combine_kernel(const float* __restrict__ shout,
                                                      const uint16_t* __restrict__ eout,
                                                      const int* __restrict__ dest,
                                                      const uint16_t* __restrict__ gating,
                                                      float* __restrict__ out) {
  const int t = blockIdx.x;
  const int d0 = threadIdx.x * 4;
  float4 sh = *(const float4*)(shout + (size_t)t * DIM + d0);
  float rx = 0.f, ry = 0.f, rz = 0.f, rw = 0.f;
#pragma unroll
  for (int k = 0; k < KSEL; k++) {
    int dp = dest[t * KSEL + k];
    if (dp >= 0) {
      float gw = bf2f(gating[t * KSEL + k]);
      ushort4 ev = *(const ushort4*)(eout + (size_t)dp * DIM + d0);
      rx += gw * bf2f(ev.x);
      ry += gw * bf2f(ev.y);
      rz += gw * bf2f(ev.z);
      rw += gw * bf2f(ev.w);
    }
  }
  float4 o;
  o.x = (sh.x + rx) * 0.5f;
  o.y = (sh.y + ry) * 0.5f;
  o.z = (sh.z + rz) * 0.5f;
  o.w = (sh.w + rw) * 0.5f;
  *(float4*)(out + (size_t)t * DIM + d0) = o;
}

extern "C" void kernel_launch(void* const* d_in, const int* in_sizes, int n_in,
                              void* d_out, int out_size, void* d_ws, size_t ws_size,
                              hipStream_t stream) {
  (void)in_sizes; (void)n_in; (void)out_size; (void)ws_size;
  const float* x   = (const float*)d_in[0];
  const float* rw  = (const float*)d_in[1];
  const float* w12 = (const float*)d_in[2];
  const float* w3  = (const float*)d_in[3];
  const float* gw  = (const float*)d_in[4];
  const float* uw  = (const float*)d_in[5];
  const float* dw  = (const float*)d_in[6];
  float* out = (float*)d_out;

  char* ws = (char*)d_ws;
  size_t off = 0;
  auto alloc = [&](size_t sz) -> void* {
    void* p = ws + off;
    off += (sz + 255) & ~(size_t)255;
    return p;
  };
  uint16_t* HB    = (uint16_t*)alloc((size_t)NTOK * DIM * 2);
  uint16_t* S1    = (uint16_t*)alloc((size_t)NTOK * DFFC * 2);
  uint16_t* ACT   = (uint16_t*)alloc((size_t)NEXP * CAPE * FF * 2);
  uint16_t* EOUT  = (uint16_t*)alloc((size_t)NEXP * CAPE * DIM * 2);
  float* SHOUT    = (float*)alloc((size_t)NTOK * DIM * 4);
  int* TOPKB      = (int*)alloc((size_t)NTOK * KSEL * 4);
  uint16_t* GATING= (uint16_t*)alloc((size_t)NTOK * KSEL * 2);
  int* DEST       = (int*)alloc((size_t)NTOK * KSEL * 4);
  int* INVMAP     = (int*)alloc((size_t)NEXP * CAPE * 4);
  int* COUNTS     = (int*)alloc((size_t)NEXP * 4);
  float* TOKZ     = (float*)alloc((size_t)NTOK * 4);

  // router / dispatch / z-loss (router also emits bf16 x)
  router_kernel<<<NTOK / 16, 256, 0, stream>>>(x, rw, TOPKB, GATING, TOKZ, HB);
  dispatch_kernel<<<NEXP, 64, 0, stream>>>(TOPKB, DEST, INVMAP, COUNTS);
  zred_kernel<<<1, 256, 0, stream>>>(TOKZ, out + (size_t)NTOK * DIM);

  // shared expert: fused gate+up SwiGLU GEMM, then down-proj
  gemm8<2, 3, false, false><<<(NTOK / 256) * (2 * DFFC / 256), 512, 0, stream>>>(
      HB, gw, uw, S1, nullptr, nullptr, DIM, DIM, DIM, DFFC, 0, 0, 0, 0,
      NTOK / 256, 2 * DFFC / 256);
  gemm8<1, 1, false, false><<<(NTOK / 256) * (DIM / 256), 512, 0, stream>>>(
      S1, dw, nullptr, SHOUT, nullptr, nullptr, DFFC, DFFC, DFFC, DIM, 0, 0, 0, 0,
      NTOK / 256, DIM / 256);

  // routed experts (grouped), fp32 K-major weights staged directly
  gemm8<2, 2, true, true><<<(CAPE / 256) * (FF2 / 256) * NEXP, 512, 0, stream>>>(
      HB, w12, nullptr, ACT, INVMAP, COUNTS, DIM, DIM, FF2, FF,
      0, (long long)DIM * FF2, (long long)CAPE * FF, 1, CAPE / 256, FF2 / 256);
  gemm8<0, 2, false, false><<<(CAPE / 256) * (DIM / 256) * NEXP, 512, 0, stream>>>(
      ACT, w3, nullptr, EOUT, nullptr, COUNTS, FF, FF, DIM, DIM,
      (long long)CAPE * FF, (long long)FF * DIM, (long long)CAPE * DIM, 1,
      CAPE / 256, DIM / 256);

  // combine
  combine_kernel<<<NTOK, 256, 0, stream>>>(SHOUT, EOUT, DEST, GATING, out);
}

// Round 8
// 773.645 us; speedup vs baseline: 1.2970x; 1.1891x over previous
//
#include <hip/hip_runtime.h>
#include <stdint.h>
#include <math.h>

#define NTOK 4096
#define DIM  1024
#define NEXP 64
#define KSEL 6
#define FF   1408
#define FF2  2816
#define DFFC 4096
#define CAPE 768

typedef __bf16 bf16x8 __attribute__((ext_vector_type(8)));
typedef float  f32x4  __attribute__((ext_vector_type(4)));

__device__ __forceinline__ float bf2f(uint32_t h) {
  union { uint32_t u; float f; } v; v.u = h << 16; return v.f;
}
__device__ __forceinline__ uint16_t f2bf(float f) {
  union { float f; uint32_t u; } v; v.f = f;
  return (uint16_t)((v.u + 0x7fffu + ((v.u >> 16) & 1u)) >> 16);
}
// packed RNE f32->bf16 pair (low = a, high = b)
__device__ __forceinline__ uint32_t pk_bf16(float a, float b) {
  uint32_t r;
  asm("v_cvt_pk_bf16_f32 %0, %1, %2" : "=v"(r) : "v"(a), "v"(b));
  return r;
}
// LDS XOR swizzle in halves (bits 3-5), proven conflict-free in r3
__device__ __forceinline__ int swzh(int r) { return ((r ^ (r >> 2)) & 7) << 3; }

__device__ __forceinline__ void load_lds16(const void* g, void* l) {
  __builtin_amdgcn_global_load_lds((const __attribute__((address_space(1))) void*)g,
                                   (__attribute__((address_space(3))) void*)l, 16, 0, 0);
}

// ---------------- router: logits, top-6, gating, z partial, bf16 x ----------------
__global__ __launch_bounds__(256) void router_kernel(const float* __restrict__ x,
                                                     const float* __restrict__ rw,
                                                     int* __restrict__ topk,
                                                     uint16_t* __restrict__ gating,
                                                     float* __restrict__ tokz,
                                                     uint16_t* __restrict__ hb) {
  __shared__ float hs[16 * DIM];
  __shared__ float lg[16][NEXP];
  const int tid = threadIdx.x;
  const int t0 = blockIdx.x * 16;
  const float4* xin = (const float4*)(x + (size_t)t0 * DIM);
  float4* hs4 = (float4*)hs;
  for (int i = tid; i < 16 * DIM / 4; i += 256) hs4[i] = xin[i];
  __syncthreads();
  {
    ushort4* hbo = (ushort4*)(hb + (size_t)t0 * DIM);
    for (int i = tid; i < 16 * DIM / 4; i += 256) {
      float4 v = hs4[i];
      ushort4 o;
      o.x = f2bf(v.x); o.y = f2bf(v.y); o.z = f2bf(v.z); o.w = f2bf(v.w);
      hbo[i] = o;
    }
  }
  const int e = tid >> 2, q = tid & 3;
  float part[16];
#pragma unroll
  for (int tt = 0; tt < 16; tt++) part[tt] = 0.f;
  const float4* rw4 = (const float4*)(rw + (size_t)e * DIM + q * 256);
  for (int i = 0; i < 64; i++) {
    float4 w = rw4[i];
#pragma unroll
    for (int tt = 0; tt < 16; tt++) {
      float4 h = *(const float4*)(hs + tt * DIM + q * 256 + i * 4);
      part[tt] += h.x * w.x + h.y * w.y + h.z * w.z + h.w * w.w;
    }
  }
#pragma unroll
  for (int tt = 0; tt < 16; tt++) {
    float v = part[tt];
    v += __shfl_xor(v, 1);
    v += __shfl_xor(v, 2);
    if (q == 0) lg[tt][e] = v;
  }
  __syncthreads();
  const int wid = tid >> 6, lane = tid & 63;
  for (int ti = 0; ti < 4; ti++) {
    int tt = wid * 4 + ti;
    float v = lg[tt][lane];
    float z = v * v;
#pragma unroll
    for (int off = 32; off; off >>= 1) z += __shfl_xor(z, off);
    float bv[KSEL]; int bi[KSEL];
#pragma unroll
    for (int s = 0; s < KSEL; s++) {
      float m = v; int mi = lane;
#pragma unroll
      for (int off = 32; off; off >>= 1) {
        float om = __shfl_xor(m, off); int oi = __shfl_xor(mi, off);
        if (om > m || (om == m && oi < mi)) { m = om; mi = oi; }
      }
      bv[s] = m; bi[s] = mi;
      if (lane == mi) v = -3.0e38f;
    }
    if (lane == 0) {
      int t = t0 + tt;
      tokz[t] = z;
      float mx = bv[0];
      float ex[KSEL], sum = 0.f;
#pragma unroll
      for (int s = 0; s < KSEL; s++) { ex[s] = expf(bv[s] - mx); sum += ex[s]; }
      float inv = 1.f / sum;
#pragma unroll
      for (int s = 0; s < KSEL; s++) {
        topk[t * KSEL + s] = bi[s];
        gating[t * KSEL + s] = f2bf(ex[s] * inv);
      }
    }
  }
}

// ---------------- z_loss reduce ----------------
__global__ __launch_bounds__(256) void zred_kernel(const float* __restrict__ tz,
                                                   float* __restrict__ out) {
  __shared__ float s[256];
  float a = 0.f;
  for (int i = threadIdx.x; i < NTOK; i += 256) a += tz[i];
  s[threadIdx.x] = a; __syncthreads();
  for (int st = 128; st; st >>= 1) {
    if (threadIdx.x < (unsigned)st) s[threadIdx.x] += s[threadIdx.x + st];
    __syncthreads();
  }
  if (threadIdx.x == 0) out[0] = s[0] * (1e-6f / ((float)NTOK * (float)NEXP));
}

// ---------------- dispatch: stable rank within expert ----------------
__global__ __launch_bounds__(64) void dispatch_kernel(const int* __restrict__ topk,
                                                      int* __restrict__ dest,
                                                      int* __restrict__ invmap,
                                                      int* __restrict__ counts) {
  const int e = blockIdx.x;
  const int lane = threadIdx.x;
  int base = 0;
  for (int it = 0; it < (NTOK * KSEL) / 64; it++) {
    int p = it * 64 + lane;
    int ex = topk[p];
    bool m = (ex == e);
    unsigned long long mask = __ballot(m);
    if (m) {
      int intra = base + __popcll(mask & ((1ull << lane) - 1ull));
      if (intra < CAPE) {
        dest[p] = e * CAPE + intra;
        invmap[e * CAPE + intra] = p / KSEL;
      } else {
        dest[p] = -1;
      }
    }
    base += __popcll(mask);
  }
  if (lane == 0) counts[e] = base < CAPE ? base : CAPE;
}

// ---------------- GEMM: C[M,N] = A[M,K] * B(op), A bf16, B fp32 cvt in staging ----
// 2-barrier loop, fully covered latencies:
//   iter t: issueA(t+1 -> sA[nb])  (DMA, full iter to land)
//           writeB(t -> sB)        (compiler vmcnt wait drains B(t) regs AND the
//                                   older A(t) DMAs -- audited, no vmcnt(0))
//           loadB(t+1 -> regs)     (T14: full iter of latency cover)
//           lgkmcnt(0); s_barrier  (publish sB; no vmem drain)
//           MFMA on sA[cur] + sB
//           s_barrier              (reads done -> sB/sA[nb] reusable)
// EPI : 0 = store bf16, 1 = store f32, 2 = SwiGLU-pair store (interleaved-16) -> bf16
// BSRC: 1 = fp32 B^T [N,K] | 2 = fp32 B [K,N] (reg transpose; REMAP = w12 interleave)
//       3 = fp32 dual B^T gate/up interleaved per 16 virtual cols
#define BM 128
#define BN 128
#define BKK 64

template<int EPI, int BSRC, bool IND, bool REMAP>
__global__ __launch_bounds__(256, 3) void gemm_f(const uint16_t* __restrict__ A,
                                                 const float* __restrict__ B,
                                                 const float* __restrict__ B2,
                                                 void* __restrict__ C,
                                                 const int* __restrict__ invmap,
                                                 const int* __restrict__ counts,
                                                 int K, int lda, int ldb, int ldc,
                                                 long long strideA, long long strideB,
                                                 long long strideC, int grouped,
                                                 int nM, int nN) {
  // XCD-chunked decode: consecutive-on-XCD blocks share (e, n) and sweep m
  const int per = gridDim.x >> 3;
  const int w = ((int)blockIdx.x & 7) * per + ((int)blockIdx.x >> 3);
  const int mi = w % nM;
  const int q1 = w / nM;
  const int ni = q1 % nN;
  const int e  = q1 / nN;
  int cnt = 1 << 30;
  if (grouped) {
    cnt = counts[e];
    if (mi * BM >= cnt) return;
  }
  const int bm0 = mi * BM, bn0 = ni * BN;
  const uint16_t* Ab = A + (size_t)e * strideA;
  const float* Bb = B + (size_t)e * strideB;
  __shared__ alignas(16) uint16_t sA[2][BM * BKK];
  __shared__ alignas(16) uint16_t sB[BN * BKK];
  const int tid = threadIdx.x, wid = tid >> 6, lane = tid & 63;

  // ---- A-side pointers (bf16, global_load_lds, source pre-swizzled) ----
  const int sa = tid >> 3;
  const int colk = (((tid & 7) ^ ((sa ^ (sa >> 2)) & 7)) * 8);
  const uint16_t* ap[4];
#pragma unroll
  for (int i = 0; i < 4; i++) {
    int row = i * 32 + sa;
    int ar = bm0 + row;
    if constexpr (IND) {
      int cr = ar < cnt ? ar : (cnt - 1);
      ar = invmap[e * CAPE + cr];
    }
    ap[i] = Ab + (size_t)ar * lda + colk;
  }

  // ---- B-side source pointers ----
  const float* bpa = nullptr;
  const float* bpb = nullptr;
  if constexpr (BSRC == 1) {
    const int kc = (tid & 15) * 4;
    bpa = Bb + (size_t)(bn0 + (tid >> 4)) * ldb + kc;
  } else if constexpr (BSRC == 3) {
    const int kc = (tid & 15) * 4;
    const int gcol = (bn0 >> 1) + (tid >> 4);
    bpa = B  + (size_t)gcol * ldb + kc;
    bpb = B2 + (size_t)gcol * ldb + kc;
  } else {
    const int n0 = 4 * (tid & 31);
    int vn0 = bn0 + n0;
    int ng0;
    if constexpr (REMAP) {
      int blk = vn0 >> 5, lo = vn0 & 31;
      ng0 = blk * 16 + (lo & 15) + (lo < 16 ? 0 : FF);
    } else {
      ng0 = vn0;
    }
    bpa = Bb + (size_t)(4 * (tid >> 5)) * ldb + ng0;
  }

  auto loadB = [&](f32x4 (&v)[8]) {
    if constexpr (BSRC == 1) {
#pragma unroll
      for (int it = 0; it < 8; it++)
        v[it] = *(const f32x4*)(bpa + (size_t)(it * 16) * ldb);
      bpa += BKK;
    } else if constexpr (BSRC == 3) {
#pragma unroll
      for (int it = 0; it < 8; it++) {
        const float* s = (it & 1) ? bpb : bpa;
        v[it] = *(const f32x4*)(s + (size_t)((it >> 1) * 16) * ldb);
      }
      bpa += BKK; bpb += BKK;
    } else {
#pragma unroll
      for (int i2 = 0; i2 < 2; i2++)
#pragma unroll
        for (int j = 0; j < 4; j++)
          v[i2 * 4 + j] = *(const f32x4*)(bpa + (size_t)(32 * i2 + j) * ldb);
      bpa += (size_t)BKK * ldb;
    }
  };
  auto issueA = [&](int buf) {
#pragma unroll
    for (int i = 0; i < 4; i++) {
      load_lds16(ap[i], sA[buf] + i * 2048 + wid * 512);
      ap[i] += BKK;
    }
  };
  auto writeB = [&](f32x4 (&v)[8]) {
    if constexpr (BSRC == 1 || BSRC == 3) {
      const int kc = (tid & 15) * 4;
#pragma unroll
      for (int it = 0; it < 8; it++) {
        int nr = (tid >> 4) + it * 16;
        uint2 p;
        p.x = pk_bf16(v[it][0], v[it][1]);
        p.y = pk_bf16(v[it][2], v[it][3]);
        *(uint2*)(sB + nr * BKK + (kc ^ swzh(nr))) = p;
      }
    } else {
      const int n0 = 4 * (tid & 31);
#pragma unroll
      for (int i2 = 0; i2 < 2; i2++) {
        int kk0 = 4 * (tid >> 5) + 32 * i2;
#pragma unroll
        for (int c = 0; c < 4; c++) {
          int nr = n0 + c;
          uint2 p;
          p.x = pk_bf16(v[i2 * 4 + 0][c], v[i2 * 4 + 1][c]);
          p.y = pk_bf16(v[i2 * 4 + 2][c], v[i2 * 4 + 3][c]);
          *(uint2*)(sB + nr * BKK + (kk0 ^ swzh(nr))) = p;
        }
      }
    }
  };

  f32x4 zero = {0.f, 0.f, 0.f, 0.f};
  f32x4 acc[4][4];
#pragma unroll
  for (int i = 0; i < 4; i++)
#pragma unroll
    for (int j = 0; j < 4; j++) acc[i][j] = zero;
  const int wm = wid >> 1, wn = wid & 1;

  f32x4 bv[8];
  // prologue: A(0) DMA + B(0) regs (only place full latency is exposed)
  issueA(0);
  loadB(bv);

  const int T = K / BKK;
  for (int t = 0; t < T; t++) {
    const int cur = t & 1, nb = cur ^ 1;
    const bool more = (t + 1 < T);
    if (more) issueA(nb);    // A(t+1) DMA: full iter to land
    writeB(bv);              // auto vmcnt wait: drains B(t) regs + older A(t) DMAs
    if (more) loadB(bv);     // B(t+1): full iter of cover
    asm volatile("s_waitcnt lgkmcnt(0)" ::: "memory");
    __builtin_amdgcn_sched_barrier(0);
    __builtin_amdgcn_s_barrier();
    __builtin_amdgcn_sched_barrier(0);
    // MFMA on sA[cur] + sB
#pragma unroll
    for (int ks = 0; ks < 2; ks++) {
      const int kb = ks * 32 + (lane >> 4) * 8;
      bf16x8 af[4], bfr[4];
#pragma unroll
      for (int f = 0; f < 4; f++) {
        int rowA = wm * 64 + f * 16 + (lane & 15);
        af[f] = *(const bf16x8*)(sA[cur] + rowA * BKK + (kb ^ swzh(rowA)));
      }
#pragma unroll
      for (int f = 0; f < 4; f++) {
        int rowB = wn * 64 + f * 16 + (lane & 15);
        bfr[f] = *(const bf16x8*)(sB + rowB * BKK + (kb ^ swzh(rowB)));
      }
#pragma unroll
      for (int fm = 0; fm < 4; fm++)
#pragma unroll
        for (int fn = 0; fn < 4; fn++)
          acc[fm][fn] = __builtin_amdgcn_mfma_f32_16x16x32_bf16(af[fm], bfr[fn],
                                                                acc[fm][fn], 0, 0, 0);
    }
    __builtin_amdgcn_sched_barrier(0);
    __builtin_amdgcn_s_barrier();
    __builtin_amdgcn_sched_barrier(0);
  }

  const int lr = (lane >> 4) * 4, lc = lane & 15;
  if constexpr (EPI == 2) {
    uint16_t* outp = (uint16_t*)C + (size_t)e * strideC;
#pragma unroll
    for (int fm = 0; fm < 4; fm++) {
#pragma unroll
      for (int fp = 0; fp < 2; fp++) {
        f32x4 g = acc[fm][2 * fp], u = acc[fm][2 * fp + 1];
        int fcol = (bn0 >> 1) + wn * 32 + fp * 16 + lc;
#pragma unroll
        for (int j = 0; j < 4; j++) {
          int r = bm0 + wm * 64 + fm * 16 + lr + j;
          float gv = g[j];
          float sv = (gv / (1.f + expf(-gv))) * u[j];
          outp[(size_t)r * ldc + fcol] = f2bf(sv);
        }
      }
    }
  } else if constexpr (EPI == 1) {
    float* outp = (float*)C + (size_t)e * strideC;
#pragma unroll
    for (int fm = 0; fm < 4; fm++)
#pragma unroll
      for (int fn = 0; fn < 4; fn++) {
        int col = bn0 + wn * 64 + fn * 16 + lc;
#pragma unroll
        for (int j = 0; j < 4; j++) {
          int r = bm0 + wm * 64 + fm * 16 + lr + j;
          outp[(size_t)r * ldc + col] = acc[fm][fn][j];
        }
      }
  } else {
    uint16_t* outp = (uint16_t*)C + (size_t)e * strideC;
#pragma unroll
    for (int fm = 0; fm < 4; fm++)
#pragma unroll
      for (int fn = 0; fn < 4; fn++) {
        int col = bn0 + wn * 64 + fn * 16 + lc;
#pragma unroll
        for (int j = 0; j < 4; j++) {
          int r = bm0 + wm * 64 + fm * 16 + lr + j;
          outp[(size_t)r * ldc + col] = f2bf(acc[fm][fn][j]);
        }
      }
  }
}

// ---------------- combine ----------------
__global__ __launch_bounds__(256) void combine_kernel(const float* __restrict__ shout,
                                                      const uint16_t* __restrict__ eout,
                                                      const int* __restrict__ dest,
                                                      const uint16_t* __restrict__ gating,
                                                      float* __restrict__ out) {
  const int t = blockIdx.x;
  const int d0 = threadIdx.x * 4;
  float4 sh = *(const float4*)(shout + (size_t)t * DIM + d0);
  float rx = 0.f, ry = 0.f, rz = 0.f, rw = 0.f;
#pragma unroll
  for (int k = 0; k < KSEL; k++) {
    int dp = dest[t * KSEL + k];
    if (dp >= 0) {
      float gw = bf2f(gating[t * KSEL + k]);
      ushort4 ev = *(const ushort4*)(eout + (size_t)dp * DIM + d0);
      rx += gw * bf2f(ev.x);
      ry += gw * bf2f(ev.y);
      rz += gw * bf2f(ev.z);
      rw += gw * bf2f(ev.w);
    }
  }
  float4 o;
  o.x = (sh.x + rx) * 0.5f;
  o.y = (sh.y + ry) * 0.5f;
  o.z = (sh.z + rz) * 0.5f;
  o.w = (sh.w + rw) * 0.5f;
  *(float4*)(out + (size_t)t * DIM + d0) = o;
}

extern "C" void kernel_launch(void* const* d_in, const int* in_sizes, int n_in,
                              void* d_out, int out_size, void* d_ws, size_t ws_size,
                              hipStream_t stream) {
  (void)in_sizes; (void)n_in; (void)out_size; (void)ws_size;
  const float* x   = (const float*)d_in[0];
  const float* rw  = (const float*)d_in[1];
  const float* w12 = (const float*)d_in[2];
  const float* w3  = (const float*)d_in[3];
  const float* gw  = (const float*)d_in[4];
  const float* uw  = (const float*)d_in[5];
  const float* dw  = (const float*)d_in[6];
  float* out = (float*)d_out;

  char* ws = (char*)d_ws;
  size_t off = 0;
  auto alloc = [&](size_t sz) -> void* {
    void* p = ws + off;
    off += (sz + 255) & ~(size_t)255;
    return p;
  };
  uint16_t* HB    = (uint16_t*)alloc((size_t)NTOK * DIM * 2);
  uint16_t* S1    = (uint16_t*)alloc((size_t)NTOK * DFFC * 2);
  uint16_t* ACT   = (uint16_t*)alloc((size_t)NEXP * CAPE * FF * 2);
  uint16_t* EOUT  = (uint16_t*)alloc((size_t)NEXP * CAPE * DIM * 2);
  float* SHOUT    = (float*)alloc((size_t)NTOK * DIM * 4);
  int* TOPKB      = (int*)alloc((size_t)NTOK * KSEL * 4);
  uint16_t* GATING= (uint16_t*)alloc((size_t)NTOK * KSEL * 2);
  int* DEST       = (int*)alloc((size_t)NTOK * KSEL * 4);
  int* INVMAP     = (int*)alloc((size_t)NEXP * CAPE * 4);
  int* COUNTS     = (int*)alloc((size_t)NEXP * 4);
  float* TOKZ     = (float*)alloc((size_t)NTOK * 4);

  // router / dispatch / z-loss (router also emits bf16 x)
  router_kernel<<<NTOK / 16, 256, 0, stream>>>(x, rw, TOPKB, GATING, TOKZ, HB);
  dispatch_kernel<<<NEXP, 64, 0, stream>>>(TOPKB, DEST, INVMAP, COUNTS);
  zred_kernel<<<1, 256, 0, stream>>>(TOKZ, out + (size_t)NTOK * DIM);

  // shared expert: fused gate+up SwiGLU GEMM, then down-proj
  gemm_f<2, 3, false, false><<<(NTOK / BM) * (2 * DFFC / BN), 256, 0, stream>>>(
      HB, gw, uw, S1, nullptr, nullptr, DIM, DIM, DIM, DFFC, 0, 0, 0, 0,
      NTOK / BM, 2 * DFFC / BN);
  gemm_f<1, 1, false, false><<<(NTOK / BM) * (DIM / BN), 256, 0, stream>>>(
      S1, dw, nullptr, SHOUT, nullptr, nullptr, DFFC, DFFC, DFFC, DIM, 0, 0, 0, 0,
      NTOK / BM, DIM / BN);

  // routed experts (grouped), fp32 K-major weights staged directly
  gemm_f<2, 2, true, true><<<(CAPE / BM) * (FF2 / BN) * NEXP, 256, 0, stream>>>(
      HB, w12, nullptr, ACT, INVMAP, COUNTS, DIM, DIM, FF2, FF,
      0, (long long)DIM * FF2, (long long)CAPE * FF, 1, CAPE / BM, FF2 / BN);
  gemm_f<0, 2, false, false><<<(CAPE / BM) * (DIM / BN) * NEXP, 256, 0, stream>>>(
      ACT, w3, nullptr, EOUT, nullptr, COUNTS, FF, FF, DIM, DIM,
      (long long)CAPE * FF, (long long)FF * DIM, (long long)CAPE * DIM, 1,
      CAPE / BM, DIM / BN);

  // combine
  combine_kernel<<<NTOK, 256, 0, stream>>>(SHOUT, EOUT, DEST, GATING, out);
}